// Round 12
// baseline (127.940 us; speedup 1.0000x reference)
//
#include <hip/hip_runtime.h>
#include <hip/hip_bf16.h>

#define B_DIM 256
#define I_DIM 128
#define O_DIM 128
#define H_DIM 32
#define F_DIM 7
#define ICHUNK 4
#define NCHUNK (I_DIM / ICHUNK)   // 32

typedef __attribute__((ext_vector_type(8))) short short8;   // 8 bf16 (4 VGPRs)
typedef __attribute__((ext_vector_type(4))) float float4v;  // MFMA C/D

__device__ inline short bf16s(float v) {
    union { __hip_bfloat16 h; short s; } u;
    u.h = __float2bfloat16(v);
    return u.s;
}

// R12 = R11 with ICHUNK 8->4 (the single change: occupancy lever).
// R11 post-mortem: 43.8us, busy ~29us vs ~25us trans-pipe floor; LDS 38.9KB
// capped residency at 4 blocks/CU (Occupancy 31%) -> ~35% issue idle.
// ICHUNK=4: LDS 19.4KB -> 8 blocks/CU (32 waves/CU); loop body identical.
//
// Silu trans-op floor (inst model): 32 exp + 32 rcp per thread-il at 1/4
// rate = 512 cyc/wave/il dominates; chip-wide ~25us at 100% issue.
//
// REGISTER-PRESSURE LAW (R2/R4/R5): __launch_bounds__(256,w) hard-caps VGPR
// at 256/w; allocator SPILLS to meet it. Demand 60 (measured R11, with MORE
// live staging state) under cap 64 fits cleanly (R3 precedent). (256,4) pins
// <=64 so VGPR doesn't cap the 8 waves/SIMD that LDS now permits.
// il-loop kept rolled (unroll 1): full unroll multiplies live ranges (R4).
__global__ __launch_bounds__(256, 4)
void fcnkan_mfma(const float* __restrict__ x,
                 const float* __restrict__ W1,
                 const float* __restrict__ W2,
                 const float* __restrict__ B1,
                 const float* __restrict__ B2,
                 float* __restrict__ out) {
    __shared__ __align__(16) short feat_s[ICHUNK * B_DIM * 8];   // 16 KB
    __shared__ __align__(16) short w1_s[ICHUNK * H_DIM * 8];     // 2 KB
    __shared__ float b1_s[ICHUNK * H_DIM];                       // 0.5 KB
    __shared__ float w2_s[ICHUNK * H_DIM];                       // 0.5 KB

    const int tid  = threadIdx.x;
    const int o    = blockIdx.x;
    const int ic0  = blockIdx.y * ICHUNK;
    const int w    = tid >> 6;       // wave: b-range [w*64, w*64+64)
    const int lane = tid & 63;
    const int m    = lane & 15;      // row/col within 16x16 tile
    const int q    = lane >> 4;      // quad

    const short8 zero8 = {};

    // ---- stage A: own x row, trig once per (b, il), bf16-pack ----
    {
        const float4* xp = reinterpret_cast<const float4*>(x + (size_t)tid * I_DIM + ic0);
        float4 x0 = xp[0];
        float xr[4] = {x0.x, x0.y, x0.z, x0.w};
        #pragma unroll
        for (int il = 0; il < ICHUNK; ++il) {
            float xv = xr[il];
            float s1 = __sinf(xv), c1 = __cosf(xv);
            float s2 = 2.f * s1 * c1, c2 = 1.f - 2.f * s1 * s1;
            float s4 = 2.f * s2 * c2, c4 = 1.f - 2.f * s2 * s2;
            short8 a;
            a[0] = bf16s(xv); a[1] = bf16s(s1); a[2] = bf16s(s2); a[3] = bf16s(s4);
            a[4] = bf16s(c1); a[5] = bf16s(c2); a[6] = bf16s(c4); a[7] = 0;
            *reinterpret_cast<short8*>(feat_s + (il * B_DIM + tid) * 8) = a;
        }
    }
    // ---- stage B: threads 0..127 <-> (il = tid>>5, h = tid&31), one W1 row ----
    if (tid < ICHUNK * H_DIM) {
        int il = tid >> 5, h = tid & 31;
        size_t iobase = (size_t)(ic0 + il) * O_DIM + o;
        const float* wr = W1 + iobase * (H_DIM * F_DIM) + h * F_DIM;
        short8 bfr;
        #pragma unroll
        for (int f = 0; f < F_DIM; ++f) bfr[f] = bf16s(wr[f]);
        bfr[7] = 0;
        *reinterpret_cast<short8*>(w1_s + tid * 8) = bfr;
        b1_s[tid] = B1[iobase * H_DIM + h];
        w2_s[tid] = W2[iobase * H_DIM + h];
    }
    __syncthreads();

    float acc[16];
    #pragma unroll
    for (int r = 0; r < 16; ++r) acc[r] = 0.f;

    #pragma unroll 1
    for (int il = 0; il < ICHUNK; ++il) {
        const short8* fS = reinterpret_cast<const short8*>(feat_s) + il * B_DIM;
        const short8* wS = reinterpret_cast<const short8*>(w1_s) + il * H_DIM;

        short8 afrag[4];
        #pragma unroll
        for (int t = 0; t < 4; ++t)
            afrag[t] = fS[w * 64 + t * 16 + m];          // ds_read_b128

        short8 bfrag[2];
        float  b1v[2], w2v[2];
        #pragma unroll
        for (int nt = 0; nt < 2; ++nt) {
            int h = nt * 16 + m;
            short8 b = wS[h];                            // ds_read_b128
            bfrag[nt] = (q == 0) ? b : zero8;            // only B quad-zeroed
            b1v[nt] = b1_s[il * H_DIM + h];
            w2v[nt] = w2_s[il * H_DIM + h];
        }

        #pragma unroll
        for (int nt = 0; nt < 2; ++nt) {
            float4v c0 = {b1v[nt], b1v[nt], b1v[nt], b1v[nt]};
            #pragma unroll
            for (int t = 0; t < 4; ++t) {
                float4v z = __builtin_amdgcn_mfma_f32_16x16x32_bf16(
                    afrag[t], bfrag[nt], c0, 0, 0, 0);
                #pragma unroll
                for (int r = 0; r < 4; ++r) {
                    float zz = z[r];
                    float sg = __builtin_amdgcn_rcpf(1.f + __expf(-zz));
                    acc[t * 4 + r] = fmaf(zz * sg, w2v[nt], acc[t * 4 + r]);
                }
            }
        }
    }

    // ---- h-sum: butterfly over the 16 lanes of each quad-group ----
    #pragma unroll
    for (int r = 0; r < 16; ++r) {
        float v = acc[r];
        v += __shfl_xor(v, 1, 64);
        v += __shfl_xor(v, 2, 64);
        v += __shfl_xor(v, 4, 64);
        v += __shfl_xor(v, 8, 64);
        acc[r] = v;
    }

    // per-chunk B2 contribution (uniform)
    float b2c = 0.f;
    for (int il = 0; il < ICHUNK; ++il) b2c += B2[(size_t)(ic0 + il) * O_DIM + o];

    // lane m==0 of each quad-group writes its 16 rows
    if (m == 0) {
        #pragma unroll
        for (int t = 0; t < 4; ++t) {
            #pragma unroll
            for (int r = 0; r < 4; ++r) {
                int b = w * 64 + t * 16 + q * 4 + r;
                atomicAdd(&out[(size_t)b * O_DIM + o], acc[t * 4 + r] + b2c);
            }
        }
    }
}

extern "C" void kernel_launch(void* const* d_in, const int* in_sizes, int n_in,
                              void* d_out, int out_size, void* d_ws, size_t ws_size,
                              hipStream_t stream) {
    const float* x  = (const float*)d_in[0];
    const float* W1 = (const float*)d_in[1];
    const float* W2 = (const float*)d_in[2];
    const float* B1 = (const float*)d_in[3];
    const float* B2 = (const float*)d_in[4];
    float* out = (float*)d_out;

    hipMemsetAsync(out, 0, (size_t)out_size * sizeof(float), stream);
    dim3 grid(O_DIM, NCHUNK);
    fcnkan_mfma<<<grid, 256, 0, stream>>>(x, W1, W2, B1, B2, out);
}

// Round 13
// 107.379 us; speedup vs baseline: 1.1915x; 1.1915x over previous
//
#include <hip/hip_runtime.h>
#include <hip/hip_bf16.h>

#define B_DIM 256
#define I_DIM 128
#define O_DIM 128
#define H_DIM 32
#define F_DIM 7
#define ICHUNK 8
#define NCHUNK (I_DIM / ICHUNK)   // 16

typedef __attribute__((ext_vector_type(8))) short short8;   // 8 bf16 (4 VGPRs)
typedef __attribute__((ext_vector_type(4))) float float4v;  // MFMA C/D

__device__ inline short bf16s(float v) {
    union { __hip_bfloat16 h; short s; } u;
    u.h = __float2bfloat16(v);
    return u.s;
}

// R13 = R11 with the atomics removed (the single change).
// R12 post-mortem: atomic cost scales hard with contention — WRITE_SIZE
// tracks atomic count exactly (~32B HBM write-through per atomicAdd;
// R9 262k=8MB, R11 524k=16MB, R12 1.05M=32MB) and doubling contention
// added ~20us idle. R13: each block stores its 256 partials (B2 folded)
// to a private ws slice ws[chunk][o][b] (2MB, L2-resident, no atomics,
// every element written -> re-poison safe); reduce_kernel sums the 16
// chunks (coalesced) and writes out directly (also kills the memset
// dispatch). Atomic fallback if ws_size < 2MB (launch-invariant).
//
// REGISTER-PRESSURE LAW (R2/R4/R5): __launch_bounds__(256,w) hard-caps VGPR
// at 256/w; the allocator SPILLS to meet it. (256,2)=cap 128 >> demand ~60.
// il-loop kept rolled (unroll 1): full unroll multiplies live ranges (R4).
template <bool USE_WS>
__global__ __launch_bounds__(256, 2)
void fcnkan_mfma(const float* __restrict__ x,
                 const float* __restrict__ W1,
                 const float* __restrict__ W2,
                 const float* __restrict__ B1,
                 const float* __restrict__ B2,
                 float* __restrict__ ws,
                 float* __restrict__ out) {
    __shared__ __align__(16) short feat_s[ICHUNK * B_DIM * 8];   // 32 KB
    __shared__ __align__(16) short w1_s[ICHUNK * H_DIM * 8];     // 4 KB
    __shared__ float b1_s[ICHUNK * H_DIM];                       // 1 KB
    __shared__ float w2_s[ICHUNK * H_DIM];                       // 1 KB

    const int tid  = threadIdx.x;
    const int o    = blockIdx.x;
    const int ic0  = blockIdx.y * ICHUNK;
    const int w    = tid >> 6;       // wave: b-range [w*64, w*64+64)
    const int lane = tid & 63;
    const int m    = lane & 15;      // row/col within 16x16 tile
    const int q    = lane >> 4;      // quad

    const short8 zero8 = {};

    // ---- stage A: own x row, trig once per (b, il), bf16-pack ----
    {
        const float4* xp = reinterpret_cast<const float4*>(x + (size_t)tid * I_DIM + ic0);
        float4 x0 = xp[0], x1 = xp[1];
        float xr[8] = {x0.x, x0.y, x0.z, x0.w, x1.x, x1.y, x1.z, x1.w};
        #pragma unroll
        for (int il = 0; il < ICHUNK; ++il) {
            float xv = xr[il];
            float s1 = __sinf(xv), c1 = __cosf(xv);
            float s2 = 2.f * s1 * c1, c2 = 1.f - 2.f * s1 * s1;
            float s4 = 2.f * s2 * c2, c4 = 1.f - 2.f * s2 * s2;
            short8 a;
            a[0] = bf16s(xv); a[1] = bf16s(s1); a[2] = bf16s(s2); a[3] = bf16s(s4);
            a[4] = bf16s(c1); a[5] = bf16s(c2); a[6] = bf16s(c4); a[7] = 0;
            *reinterpret_cast<short8*>(feat_s + (il * B_DIM + tid) * 8) = a;
        }
    }
    // ---- stage B: thread tid <-> (il = tid>>5, h = tid&31), one W1 row ----
    {
        int il = tid >> 5, h = tid & 31;
        size_t iobase = (size_t)(ic0 + il) * O_DIM + o;
        const float* wr = W1 + iobase * (H_DIM * F_DIM) + h * F_DIM;
        short8 bfr;
        #pragma unroll
        for (int f = 0; f < F_DIM; ++f) bfr[f] = bf16s(wr[f]);
        bfr[7] = 0;
        *reinterpret_cast<short8*>(w1_s + tid * 8) = bfr;
        b1_s[tid] = B1[iobase * H_DIM + h];
        w2_s[tid] = W2[iobase * H_DIM + h];
    }
    __syncthreads();

    float acc[16];
    #pragma unroll
    for (int r = 0; r < 16; ++r) acc[r] = 0.f;

    #pragma unroll 1
    for (int il = 0; il < ICHUNK; ++il) {
        const short8* fS = reinterpret_cast<const short8*>(feat_s) + il * B_DIM;
        const short8* wS = reinterpret_cast<const short8*>(w1_s) + il * H_DIM;

        short8 afrag[4];
        #pragma unroll
        for (int t = 0; t < 4; ++t)
            afrag[t] = fS[w * 64 + t * 16 + m];          // ds_read_b128

        short8 bfrag[2];
        float  b1v[2], w2v[2];
        #pragma unroll
        for (int nt = 0; nt < 2; ++nt) {
            int h = nt * 16 + m;
            short8 b = wS[h];                            // ds_read_b128
            bfrag[nt] = (q == 0) ? b : zero8;            // only B quad-zeroed
            b1v[nt] = b1_s[il * H_DIM + h];
            w2v[nt] = w2_s[il * H_DIM + h];
        }

        #pragma unroll
        for (int nt = 0; nt < 2; ++nt) {
            float4v c0 = {b1v[nt], b1v[nt], b1v[nt], b1v[nt]};
            #pragma unroll
            for (int t = 0; t < 4; ++t) {
                float4v z = __builtin_amdgcn_mfma_f32_16x16x32_bf16(
                    afrag[t], bfrag[nt], c0, 0, 0, 0);
                #pragma unroll
                for (int r = 0; r < 4; ++r) {
                    float zz = z[r];
                    float sg = __builtin_amdgcn_rcpf(1.f + __expf(-zz));
                    acc[t * 4 + r] = fmaf(zz * sg, w2v[nt], acc[t * 4 + r]);
                }
            }
        }
    }

    // ---- h-sum: butterfly over the 16 lanes of each quad-group ----
    #pragma unroll
    for (int r = 0; r < 16; ++r) {
        float v = acc[r];
        v += __shfl_xor(v, 1, 64);
        v += __shfl_xor(v, 2, 64);
        v += __shfl_xor(v, 4, 64);
        v += __shfl_xor(v, 8, 64);
        acc[r] = v;
    }

    // per-chunk B2 contribution (uniform)
    float b2c = 0.f;
    for (int il = 0; il < ICHUNK; ++il) b2c += B2[(size_t)(ic0 + il) * O_DIM + o];

    // lane m==0 of each quad-group writes its 16 rows (plain stores; the
    // block covers a contiguous 1 KB ws slice -> L2 coalesces the lines)
    if (m == 0) {
        if (USE_WS) {
            float* wsp = ws + ((size_t)blockIdx.y * O_DIM + o) * B_DIM;
            #pragma unroll
            for (int t = 0; t < 4; ++t)
                #pragma unroll
                for (int r = 0; r < 4; ++r)
                    wsp[w * 64 + t * 16 + q * 4 + r] = acc[t * 4 + r] + b2c;
        } else {
            #pragma unroll
            for (int t = 0; t < 4; ++t)
                #pragma unroll
                for (int r = 0; r < 4; ++r) {
                    int b = w * 64 + t * 16 + q * 4 + r;
                    atomicAdd(&out[(size_t)b * O_DIM + o], acc[t * 4 + r] + b2c);
                }
        }
    }
}

// Sum the NCHUNK partials per (o,b). Reads coalesced (256 consecutive
// floats per chunk per block); 2 MB total, L2-resident.
__global__ __launch_bounds__(256)
void reduce_kernel(const float* __restrict__ ws, float* __restrict__ out) {
    const int o = blockIdx.x;
    const int b = threadIdx.x;
    float s = 0.f;
    #pragma unroll
    for (int c = 0; c < NCHUNK; ++c)
        s += ws[((size_t)c * O_DIM + o) * B_DIM + b];
    out[(size_t)b * O_DIM + o] = s;
}

extern "C" void kernel_launch(void* const* d_in, const int* in_sizes, int n_in,
                              void* d_out, int out_size, void* d_ws, size_t ws_size,
                              hipStream_t stream) {
    const float* x  = (const float*)d_in[0];
    const float* W1 = (const float*)d_in[1];
    const float* W2 = (const float*)d_in[2];
    const float* B1 = (const float*)d_in[3];
    const float* B2 = (const float*)d_in[4];
    float* out = (float*)d_out;
    float* ws  = (float*)d_ws;

    const size_t ws_need = (size_t)NCHUNK * O_DIM * B_DIM * sizeof(float); // 2 MiB
    dim3 grid(O_DIM, NCHUNK);
    if (ws_size >= ws_need) {   // launch-invariant -> graph-safe
        fcnkan_mfma<true><<<grid, 256, 0, stream>>>(x, W1, W2, B1, B2, ws, out);
        reduce_kernel<<<O_DIM, B_DIM, 0, stream>>>(ws, out);
    } else {
        hipMemsetAsync(out, 0, (size_t)out_size * sizeof(float), stream);
        fcnkan_mfma<false><<<grid, 256, 0, stream>>>(x, W1, W2, B1, B2, ws, out);
    }
}